// Round 5
// baseline (12743.823 us; speedup 1.0000x reference)
//
#include <hip/hip_runtime.h>

#define NP   19
#define EPB  16
#define BLK  256
#define WST  260        // s_W row stride (words): mult of 4 (float4 reads) + pad
#define RSTRIDE 4864    // P_TOTAL = 19*256 columns in R

namespace {
constexpr int P_IO[NP]  = {0,0,0, 1,1,1,1,1,1,1, 2,2,2,2, 2,2,2,2,2};
constexpr int P_II[NP]  = {0,1,2, 0,1,1,1,2,2,2, 0,1,1,1, 2,2,2,2,2};
constexpr int P_LF[NP]  = {0,1,2, 1,0,1,2,1,2,3, 2,1,2,3, 0,1,2,3,4};
constexpr int P_CGB[NP] = {0,1,10, 35,44,53,80,125,170,245, 350,375,420,495, 600,625,700,825,1000};
constexpr float NORMLF[5] = {1.0f, 0.57735026918962576f, 0.44721359549995794f,
                             0.37796447300922722f, 0.33333333333333333f};
}

template<int P>
__device__ __forceinline__ void process_path(
    const int tid, const int l, const int eloc,
    const float fA, const float (&fB)[3], const float (&fC)[5],
    const float (&y)[25], float (&acc)[9],
    const float* __restrict__ R, const float* __restrict__ s_cg,
    const float (*__restrict__ s_rad)[10],
    float (*__restrict__ s_cgy)[25], float (*__restrict__ s_tmp)[84],
    float* __restrict__ s_W)
{
    constexpr int io = P_IO[P], ii = P_II[P], lf = P_LF[P];
    constexpr int dO = 2*io+1, dI = 2*ii+1, dF = 2*lf+1;
    constexpr int nOI = dO*dI, yb = lf*lf;
    constexpr float nrm = NORMLF[lf];
    constexpr int buf = (P & 1) * (EPB * WST);

    // ---- stage 1a: cooperative W tile. thread tid owns column c=tid of 256.
    {
        float rcol[10];
        const float* Rp = R + P*256 + tid;
#pragma unroll
        for (int r = 0; r < 10; ++r) rcol[r] = Rp[r * RSTRIDE];
#pragma unroll
        for (int e = 0; e < EPB; ++e) {
            float s = 0.f;
#pragma unroll
            for (int r = 0; r < 10; ++r) s += s_rad[e][r] * rcol[r];
            s_W[buf + e*WST + tid] = s;
        }
    }

    // ---- stage 1b: cgY[o,i] = norm * sum_f cg[o,i,f] * Y[f]
#pragma unroll
    for (int j0 = 0; j0 < nOI; j0 += 16) {
        const int j = j0 + l;
        if (j < nOI) {
            float s = 0.f;
#pragma unroll
            for (int f = 0; f < dF; ++f)
                s += s_cg[P_CGB[P] + j*dF + f] * y[yb + f];
            s_cgy[eloc][j] = s * nrm;
        }
    }
    __syncthreads();

    // ---- stage 2: tmp[v,o] = sum_i F[v,i] * cgY[o,i]   (lane = v)
#pragma unroll
    for (int o = 0; o < dO; ++o) {
        float t = 0.f;
#pragma unroll
        for (int i = 0; i < dI; ++i) {
            float fv;
            if constexpr (ii == 0)      fv = fA;
            else if constexpr (ii == 1) fv = fB[i];
            else                        fv = fC[i];
            t += fv * s_cgy[eloc][o*dI + i];
        }
        s_tmp[eloc][o*16 + l] = t;
    }
    __syncthreads();

    // ---- stage 3: out[w,o] += sum_v W[w,v] * tmp[v,o]   (lane = w)
    const float* Wrow = &s_W[buf + eloc*WST + 16*l];
    const float4 w0 = *reinterpret_cast<const float4*>(Wrow);
    const float4 w1 = *reinterpret_cast<const float4*>(Wrow + 4);
    const float4 w2 = *reinterpret_cast<const float4*>(Wrow + 8);
    const float4 w3 = *reinterpret_cast<const float4*>(Wrow + 12);
#pragma unroll
    for (int o = 0; o < dO; ++o) {
        const float4* tq = reinterpret_cast<const float4*>(&s_tmp[eloc][o*16]);
        const float4 t0 = tq[0], t1 = tq[1], t2 = tq[2], t3 = tq[3];
        float s = w0.x*t0.x + w0.y*t0.y + w0.z*t0.z + w0.w*t0.w
                + w1.x*t1.x + w1.y*t1.y + w1.z*t1.z + w1.w*t1.w
                + w2.x*t2.x + w2.y*t2.y + w2.z*t2.z + w2.w*t2.w
                + w3.x*t3.x + w3.y*t3.y + w3.z*t3.z + w3.w*t3.w;
        acc[io*io + o] += s;
    }
}

template<int P>
__device__ __forceinline__ void process_all(
    const int tid, const int l, const int eloc,
    const float fA, const float (&fB)[3], const float (&fC)[5],
    const float (&y)[25], float (&acc)[9],
    const float* __restrict__ R, const float* __restrict__ s_cg,
    const float (*__restrict__ s_rad)[10],
    float (*__restrict__ s_cgy)[25], float (*__restrict__ s_tmp)[84],
    float* __restrict__ s_W)
{
    if constexpr (P < NP) {
        process_path<P>(tid, l, eloc, fA, fB, fC, y, acc, R, s_cg, s_rad, s_cgy, s_tmp, s_W);
        process_all<P+1>(tid, l, eloc, fA, fB, fC, y, acc, R, s_cg, s_rad, s_cgy, s_tmp, s_W);
    }
}

// ======== CSR build (by destination) ========
__global__ void k_count(const int* __restrict__ Ma, int* __restrict__ cur, int E) {
    int e = blockIdx.x * blockDim.x + threadIdx.x;
    if (e < E) atomicAdd(&cur[Ma[e]], 1);
}

__global__ void k_scan(int* __restrict__ cur, int* __restrict__ off, int N) {
    __shared__ int part[BLK];
    const int t = threadIdx.x;
    const int K = (N + BLK - 1) / BLK;
    const int i0 = t * K, i1 = min(i0 + K, N);
    int s = 0;
    for (int i = i0; i < i1; ++i) s += cur[i];
    part[t] = s;
    __syncthreads();
    if (t == 0) {
        int a = 0;
        for (int j = 0; j < BLK; ++j) { int v = part[j]; part[j] = a; a += v; }
        off[N] = a;
    }
    __syncthreads();
    int a = part[t];
    for (int i = i0; i < i1; ++i) {
        int v = cur[i];
        off[i] = a;
        cur[i] = a;       // reset as scatter cursor
        a += v;
    }
}

__global__ void k_scatter(const int* __restrict__ Ma, int* __restrict__ cur,
                          int* __restrict__ eidx, int E) {
    int e = blockIdx.x * blockDim.x + threadIdx.x;
    if (e < E) {
        int pos = atomicAdd(&cur[Ma[e]], 1);
        eidx[pos] = e;
    }
}

// ======== main: one block per destination node ========
__global__ __launch_bounds__(BLK, 3)
void se3_conv_node(const float* __restrict__ F, const float* __restrict__ R,
                   const float* __restrict__ Ys, const float* __restrict__ Rad,
                   const float* __restrict__ cg, const float* __restrict__ Nn,
                   const int* __restrict__ Mb,
                   const int* __restrict__ off, const int* __restrict__ eidx,
                   float* __restrict__ Out)
{
    __shared__ float s_cg[1225];
    __shared__ float s_rad[EPB][10];
    __shared__ float s_cgy[EPB][25];
    __shared__ float s_tmp[EPB][84];
    __shared__ float s_W[2 * EPB * WST];   // double-buffered W; epilogue aliases s_x

    const int tid  = threadIdx.x;
    const int l    = tid & 15;
    const int eloc = tid >> 4;
    const int n    = blockIdx.x;

    for (int j = tid; j < 1225; j += BLK) s_cg[j] = cg[j];

    const int ro0 = off[n];
    const int ro1 = off[n + 1];
    const int nChunk = (ro1 - ro0 + EPB - 1) / EPB;

    float acc[9];
#pragma unroll
    for (int k = 0; k < 9; ++k) acc[k] = 0.f;

    for (int c = 0; c < nChunk; ++c) {
        const int  idx    = ro0 + c * EPB + eloc;
        const bool act    = (idx < ro1);
        const int  eid    = act ? eidx[idx] : 0;   // slot's edge (broadcast within 16 lanes)
        const int  b      = Mb[eid];

        // per-slot radii (inactive slots zeroed -> W contribution is exactly 0)
        if (l < 10) s_rad[eloc][l] = act ? Rad[eid * 10 + l] : 0.f;

        const float* Fb = F + b * 144;
        const float fA = Fb[l];
        float fB[3], fC[5];
#pragma unroll
        for (int i = 0; i < 3; ++i) fB[i] = Fb[16 + l*3 + i];
#pragma unroll
        for (int i = 0; i < 5; ++i) fC[i] = Fb[64 + l*5 + i];

        float y[25];
        const float* yrow = Ys + (size_t)eid * 25;
#pragma unroll
        for (int k = 0; k < 25; ++k) y[k] = yrow[k];

        __syncthreads();   // s_rad ready; prev-chunk s_W/s_tmp reads done; s_cg staged (c==0)

        process_all<0>(tid, l, eloc, fA, fB, fC, y, acc, R, s_cg, s_rad, s_cgy, s_tmp, &s_W[0]);
    }

    // ---- epilogue: cross-slot reduction in LDS, single coalesced row store ----
    __syncthreads();                 // last stage-3 s_W reads done; safe to alias
    float* s_x = &s_W[0];            // s_x[slot][144]
    {
        float* xr = &s_x[eloc * 144];
        xr[l] = acc[0];
#pragma unroll
        for (int o = 0; o < 3; ++o) xr[16 + l*3 + o] = acc[1+o];
#pragma unroll
        for (int o = 0; o < 5; ++o) xr[64 + l*5 + o] = acc[4+o];
    }
    __syncthreads();
    if (tid < 144) {
        float s = 0.f;
#pragma unroll
        for (int sl = 0; sl < EPB; ++sl) s += s_x[sl * 144 + tid];
        Out[(size_t)n * 144 + tid] = s * Nn[n];
    }
}

extern "C" void kernel_launch(void* const* d_in, const int* in_sizes, int n_in,
                              void* d_out, int out_size, void* d_ws, size_t ws_size,
                              hipStream_t stream) {
    const float* F   = (const float*)d_in[0];
    const float* R   = (const float*)d_in[1];
    const float* Ys  = (const float*)d_in[2];
    const float* Rad = (const float*)d_in[3];
    const float* cg  = (const float*)d_in[4];
    const float* Nn  = (const float*)d_in[5];
    const int*   Ma  = (const int*)d_in[6];
    const int*   Mb  = (const int*)d_in[7];
    float* Out = (float*)d_out;

    const int nE = in_sizes[6];   // edges
    const int nN = in_sizes[5];   // nodes (n_norm length)

    int* wsI  = (int*)d_ws;
    int* cur  = wsI;              // [nN]   counts, then scatter cursors
    int* off  = wsI + nN;         // [nN+1] row offsets
    int* eidx = wsI + 2*nN + 1;   // [nE]   edge ids sorted by destination

    hipMemsetAsync(cur, 0, (size_t)nN * sizeof(int), stream);
    k_count  <<<(nE + BLK - 1) / BLK, BLK, 0, stream>>>(Ma, cur, nE);
    k_scan   <<<1, BLK, 0, stream>>>(cur, off, nN);
    k_scatter<<<(nE + BLK - 1) / BLK, BLK, 0, stream>>>(Ma, cur, eidx, nE);

    se3_conv_node<<<nN, BLK, 0, stream>>>(F, R, Ys, Rad, cg, Nn, Mb, off, eidx, Out);
}